// Round 12
// baseline (244.950 us; speedup 1.0000x reference)
//
#include <hip/hip_runtime.h>
#include <hip/hip_bf16.h>
#include <stdint.h>

// ---------------------------------------------------------------------------
// OneEventExtracter: proj GEMM (f32 in -> bf16 MFMA) + RoPE + 62-head QK^T.
// B=16, L=256, H=1024, heads: [tri, arg, role0..59], head_dim=64.
// Inputs f32, OUTPUTS FLOAT32. Masked slots = bf16-cast -1e12 exactly.
// R12: role3 at 1024 threads (16 waves, 2 blocks/CU -> 100% occupancy;
// serial head chain per wave halves to 3-4). Everything else = R11
// (nt output stores, tiled proj_pre + XCD swizzle, preconv).
// ---------------------------------------------------------------------------

typedef __attribute__((ext_vector_type(8)))  short short8;
typedef __attribute__((ext_vector_type(4)))  float f32x4;
typedef __attribute__((ext_vector_type(4)))  uint16_t u16x4;

#define LQ    256
#define HID   1024
#define NH    62                   // heads
#define HSTR  16384                // 256 tokens * 64 dims, per head per batch
#define NEGF  (-1000727379968.0f)  // bf16(-1e12) as f32 — matches bf16-cast ref
#define TA_OFF   1048576ULL        // arg output offset (f32 elems)
#define ROLE_OFF 2097152ULL        // role output offset (f32 elems)

__device__ __forceinline__ uint16_t f2bf(float x) {          // RNE
  uint32_t u = __builtin_bit_cast(uint32_t, x);
  return (uint16_t)((u + 0x7FFFu + ((u >> 16) & 1u)) >> 16);
}
__device__ __forceinline__ uint16_t f2bf_tr(float x) {       // truncate (GEMM in)
  return (uint16_t)(__builtin_bit_cast(uint32_t, x) >> 16);
}
__device__ __forceinline__ float bf2f(uint16_t b) {
  uint32_t u = ((uint32_t)b) << 16;
  return __builtin_bit_cast(float, u);
}
__device__ __forceinline__ int mask_mode(const void* p) {
  uint32_t w0 = *(const uint32_t*)p;
  if (w0 == 0x01010101u) return 0;   // bool bytes
  if (w0 == 1u)          return 1;   // int32
  if (w0 == 0x3F803F80u) return 2;   // bf16
  return 3;                          // f32
}
__device__ __forceinline__ bool mask_at(const void* p, int mode, size_t idx) {
  if (mode == 0) return ((const uint8_t*)p)[idx] != 0;
  if (mode == 1) return ((const int*)p)[idx] != 0;
  if (mode == 2) return (((const uint16_t*)p)[idx] & 0x7FFFu) != 0;
  return ((const float*)p)[idx] != 0.0f;
}
__device__ __forceinline__ void rope_cs(int pos, float invf, float* s, float* c) {
  float ang = (float)pos * invf;
  __sincosf(ang, s, c);
}
__device__ __forceinline__ float rope_invf(int p) {
  return exp2f(-(float)p * (13.287712379549449f / 32.0f));
}
__device__ __forceinline__ void gload16(const short* g, short* l) {
  __builtin_amdgcn_global_load_lds(
      (const __attribute__((address_space(1))) void*)g,
      (__attribute__((address_space(3))) void*)l, 16, 0, 0);
}
// m204 bijective XCD swizzle: contiguous work range per XCD.
__device__ __forceinline__ int xcd_swizzle(int l, int nwg) {
  int xcd = l & 7, idx = l >> 3;
  int q = nwg >> 3, r = nwg & 7;
  int base = (xcd < r) ? xcd * (q + 1) : r * (q + 1) + (xcd - r) * q;
  return base + idx;
}

// ---------------------------------------------------------------------------
// Preconvert to TILED bf16: tile = [16 rows][32 k] = 512 elems = 1KB.
// ---------------------------------------------------------------------------
#define EGRP 524288                    // 4096*1024/8
#define WGRP 1015808                   // 7936*1024/8
__global__ __launch_bounds__(256)
void k_preconv(const float* __restrict__ E,
               const float* __restrict__ triW, const float* __restrict__ argW,
               const float* __restrict__ roleW,
               short* __restrict__ Eb, short* __restrict__ Wb) {
  for (int gid = blockIdx.x * 256 + threadIdx.x; gid < EGRP + WGRP;
       gid += gridDim.x * 256) {
    const float* src;
    short* dst;
    if (gid < EGRP) {
      int row = gid >> 7, col8 = gid & 127;
      src = E + (size_t)row * HID + col8 * 8;
      dst = Eb + (((size_t)(row >> 4)) * 32 + (col8 >> 2)) * 512
               + (row & 15) * 32 + (col8 & 3) * 8;
    } else {
      int g = gid - EGRP;
      int row = g >> 7, col8 = g & 127;
      const float* srow = (row < 128) ? triW + (size_t)row * HID
                        : (row < 256) ? argW + (size_t)(row - 128) * HID
                                      : roleW + (size_t)(row - 256) * HID;
      src = srow + col8 * 8;
      dst = Wb + (((size_t)(row >> 4)) * 32 + (col8 >> 2)) * 512
               + (row & 15) * 32 + (col8 & 3) * 8;
    }
    f32x4 v0 = *reinterpret_cast<const f32x4*>(src);
    f32x4 v1 = *reinterpret_cast<const f32x4*>(src + 4);
    short8 r;
    r[0] = (short)f2bf_tr(v0[0]); r[1] = (short)f2bf_tr(v0[1]);
    r[2] = (short)f2bf_tr(v0[2]); r[3] = (short)f2bf_tr(v0[3]);
    r[4] = (short)f2bf_tr(v1[0]); r[5] = (short)f2bf_tr(v1[1]);
    r[6] = (short)f2bf_tr(v1[2]); r[7] = (short)f2bf_tr(v1[3]);
    *reinterpret_cast<short8*>(dst) = r;
  }
}

// ---------------------------------------------------------------------------
// Proj GEMM (tiled bf16, global_load_lds 1KB bursts): 128x128 tile, BK=32.
// grid: (62, 2*cb), XCD-swizzled. RoPE epilogue -> qs/ks [c][head][token][64].
// ---------------------------------------------------------------------------
__global__ __launch_bounds__(256)
void k_proj_pre(const short* __restrict__ Eb, const short* __restrict__ Wb,
                const float* __restrict__ triB, const float* __restrict__ argB,
                const float* __restrict__ roleB,
                short* __restrict__ qs, short* __restrict__ ks, int b0) {
  const int nwg = 62 * gridDim.y;
  const int nl  = xcd_swizzle(blockIdx.x + 62 * blockIdx.y, nwg);
  const int nb = nl % 62;             // 0..61
  const int mb = nl / 62;             // chunk-local 128-row tile
  const int n0 = nb * 128;
  const int mrow0 = b0 * LQ + mb * 128;
  const int lrow0 = mb * 128;

  const float* Bv;
  if (nb == 0)      Bv = triB;
  else if (nb == 1) Bv = argB;
  else              Bv = roleB + (n0 - 256);

  __shared__ short As[2][128 * 32];
  __shared__ short Bs[2][128 * 32];

  const int tid  = threadIdx.x;
  const int lane = tid & 63;
  const int w    = tid >> 6;
  const int wm   = (w >> 1) * 64, wn = (w & 1) * 64;
  const int l8   = lane * 8;
  const int mt0  = mrow0 >> 4;        // 16-row tile base (A)
  const int nt0  = n0 >> 4;           // 16-row tile base (B)

  f32x4 acc[4][4] = {};

  auto stage = [&](int buf, int kt) {
#pragma unroll
    for (int cc = 0; cc < 2; ++cc) {
      const int c = w * 2 + cc;        // 16-row subtile 0..7
      gload16(Eb + ((size_t)(mt0 + c) * 32 + kt) * 512 + l8, &As[buf][c * 512]);
      gload16(Wb + ((size_t)(nt0 + c) * 32 + kt) * 512 + l8, &Bs[buf][c * 512]);
    }
  };

  stage(0, 0);
  __syncthreads();
  for (int t = 0; t < 32; ++t) {
    const int buf = t & 1;
    if (t + 1 < 32) stage(buf ^ 1, t + 1);
    short8 af[4], bfr[4];
#pragma unroll
    for (int i = 0; i < 4; ++i)
      af[i] = *reinterpret_cast<const short8*>(
          &As[buf][(wm + i * 16 + (lane & 15)) * 32 + (lane >> 4) * 8]);
#pragma unroll
    for (int j = 0; j < 4; ++j)
      bfr[j] = *reinterpret_cast<const short8*>(
          &Bs[buf][(wn + j * 16 + (lane & 15)) * 32 + (lane >> 4) * 8]);
#pragma unroll
    for (int i = 0; i < 4; ++i)
#pragma unroll
      for (int j = 0; j < 4; ++j)
        acc[i][j] = __builtin_amdgcn_mfma_f32_16x16x32_bf16(af[i], bfr[j], acc[i][j], 0, 0, 0);
    __syncthreads();
  }

  // Epilogue: bias + RoPE + scatter bf16 to [c][head][token][64].
  const int col_l = lane & 15;
  const int row_h = (lane >> 4) * 4;
#pragma unroll
  for (int j = 0; j < 4; ++j) {
    const int n_loc = wn + j * 16 + col_l;
    const int gcol  = n0 + n_loc;
    const float bias = Bv[n_loc];
    const int d    = gcol & 63;
    const int head = gcol >> 7;
    const bool is_k = (gcol >> 6) & 1;
    const bool odd = d & 1;
    const float invf = rope_invf(d >> 1);
    short* dst = is_k ? ks : qs;
#pragma unroll
    for (int i = 0; i < 4; ++i) {
#pragma unroll
      for (int r = 0; r < 4; ++r) {
        float v  = acc[i][j][r] + bias;
        float vp = __shfl_xor(v, 1, 64);
        int tl  = lrow0 + wm + i * 16 + row_h + r;   // chunk-local token row
        int pos = tl & (LQ - 1);
        float s, c;
        rope_cs(pos, invf, &s, &c);
        float o = odd ? (v * c + vp * s) : (v * c - vp * s);
        dst[((size_t)(tl >> 8) * NH + head) * HSTR + (size_t)pos * 64 + d] =
            (short)f2bf(o);
      }
    }
  }
}

// ---------------------------------------------------------------------------
// Fallback proj (f32 inputs, reg-staged cvt) — same epilogue layout.
// ---------------------------------------------------------------------------
__global__ __launch_bounds__(256)
void k_proj_chunk(const float* __restrict__ E,
                  const float* __restrict__ triW, const float* __restrict__ triB,
                  const float* __restrict__ argW, const float* __restrict__ argB,
                  const float* __restrict__ roleW, const float* __restrict__ roleB,
                  short* __restrict__ qs, short* __restrict__ ks, int b0) {
  const int nb = blockIdx.x;
  const int mb = blockIdx.y;
  const int n0 = nb * 128;
  const int mrow0 = b0 * LQ + mb * 128;
  const int lrow0 = mb * 128;

  const float* W;  const float* Bv;
  if (nb == 0)      { W = triW;                             Bv = triB; }
  else if (nb == 1) { W = argW;                             Bv = argB; }
  else              { W = roleW + (size_t)(n0 - 256) * HID; Bv = roleB + (n0 - 256); }

  __shared__ short As[2][128 * 32];
  __shared__ short Bs[2][128 * 32];

  const int tid  = threadIdx.x;
  const int lane = tid & 63;
  const int w    = tid >> 6;
  const int wm   = (w >> 1) * 64, wn = (w & 1) * 64;
  const int srow = tid >> 2;
  const int scol = (tid & 3) * 8;

  f32x4 acc[4][4] = {};
  f32x4 ra0[2], ra1[2], rb0[2], rb1[2];

  auto load_regs = [&](int k0) {
    const float* pa0 = E + (size_t)(mrow0 + srow) * HID + k0 + scol;
    const float* pa1 = E + (size_t)(mrow0 + 64 + srow) * HID + k0 + scol;
    const float* pb0 = W + (size_t)(srow) * HID + k0 + scol;
    const float* pb1 = W + (size_t)(64 + srow) * HID + k0 + scol;
    ra0[0] = *reinterpret_cast<const f32x4*>(pa0);
    ra0[1] = *reinterpret_cast<const f32x4*>(pa0 + 4);
    ra1[0] = *reinterpret_cast<const f32x4*>(pa1);
    ra1[1] = *reinterpret_cast<const f32x4*>(pa1 + 4);
    rb0[0] = *reinterpret_cast<const f32x4*>(pb0);
    rb0[1] = *reinterpret_cast<const f32x4*>(pb0 + 4);
    rb1[0] = *reinterpret_cast<const f32x4*>(pb1);
    rb1[1] = *reinterpret_cast<const f32x4*>(pb1 + 4);
  };
  auto cvt8 = [&](const f32x4* v) -> short8 {
    short8 r;
    r[0] = (short)f2bf_tr(v[0][0]); r[1] = (short)f2bf_tr(v[0][1]);
    r[2] = (short)f2bf_tr(v[0][2]); r[3] = (short)f2bf_tr(v[0][3]);
    r[4] = (short)f2bf_tr(v[1][0]); r[5] = (short)f2bf_tr(v[1][1]);
    r[6] = (short)f2bf_tr(v[1][2]); r[7] = (short)f2bf_tr(v[1][3]);
    return r;
  };
  auto write_lds = [&](int buf) {
    *reinterpret_cast<short8*>(&As[buf][srow * 32 + scol])        = cvt8(ra0);
    *reinterpret_cast<short8*>(&As[buf][(64 + srow) * 32 + scol]) = cvt8(ra1);
    *reinterpret_cast<short8*>(&Bs[buf][srow * 32 + scol])        = cvt8(rb0);
    *reinterpret_cast<short8*>(&Bs[buf][(64 + srow) * 32 + scol]) = cvt8(rb1);
  };

  load_regs(0); write_lds(0); __syncthreads();
  const int NT = HID / 32;
  for (int t = 0; t < NT; ++t) {
    if (t + 1 < NT) load_regs((t + 1) * 32);
    const int buf = t & 1;
    short8 af[4], bfr[4];
#pragma unroll
    for (int i = 0; i < 4; ++i)
      af[i] = *reinterpret_cast<const short8*>(
          &As[buf][(wm + i * 16 + (lane & 15)) * 32 + (lane >> 4) * 8]);
#pragma unroll
    for (int j = 0; j < 4; ++j)
      bfr[j] = *reinterpret_cast<const short8*>(
          &Bs[buf][(wn + j * 16 + (lane & 15)) * 32 + (lane >> 4) * 8]);
#pragma unroll
    for (int i = 0; i < 4; ++i)
#pragma unroll
      for (int j = 0; j < 4; ++j)
        acc[i][j] = __builtin_amdgcn_mfma_f32_16x16x32_bf16(af[i], bfr[j], acc[i][j], 0, 0, 0);
    __syncthreads();
    if (t + 1 < NT) { write_lds((t + 1) & 1); __syncthreads(); }
  }

  const int col_l = lane & 15;
  const int row_h = (lane >> 4) * 4;
#pragma unroll
  for (int j = 0; j < 4; ++j) {
    const int n_loc = wn + j * 16 + col_l;
    const int gcol  = n0 + n_loc;
    const float bias = Bv[n_loc];
    const int d    = gcol & 63;
    const int head = gcol >> 7;
    const bool is_k = (gcol >> 6) & 1;
    const bool odd = d & 1;
    const float invf = rope_invf(d >> 1);
    short* dst = is_k ? ks : qs;
#pragma unroll
    for (int i = 0; i < 4; ++i) {
#pragma unroll
      for (int r = 0; r < 4; ++r) {
        float v  = acc[i][j][r] + bias;
        float vp = __shfl_xor(v, 1, 64);
        int tl  = lrow0 + wm + i * 16 + row_h + r;
        int pos = tl & (LQ - 1);
        float s, c;
        rope_cs(pos, invf, &s, &c);
        float o = odd ? (v * c + vp * s) : (v * c - vp * s);
        dst[((size_t)(tl >> 8) * NH + head) * HSTR + (size_t)pos * 64 + d] =
            (short)f2bf(o);
      }
    }
  }
}

// ---------------------------------------------------------------------------
// Role logits v6: 1024 thr (16 waves, 2 blocks/CU = 100% occupancy).
// Heads {12x4, 4x3}; 60KB tile; nt f32x4 writeout. grid: (8, 16, cb).
// ---------------------------------------------------------------------------
__global__ __launch_bounds__(1024)
void k_role6(const short* __restrict__ qs, const short* __restrict__ ks,
             const void* __restrict__ triu_mask, float* __restrict__ out,
             int b0) {
  const int nwg = gridDim.z * 128;    // always divisible by 8
  const int nl  = xcd_swizzle(blockIdx.x + 8 * blockIdx.y + 128 * blockIdx.z,
                              nwg);
  const int bz  = nl >> 7;
  const int rem = nl & 127;
  const int mt  = rem >> 3, nt = rem & 7;
  const int bg = b0 + bz;
  const int m0 = mt * 16, n0 = nt * 32;
  __shared__ uint16_t tile[16 * 32 * 60];   // 60 KB

  const int tid = threadIdx.x, lane = tid & 63, w = tid >> 6;   // w 0..15
  const int frow = lane & 15;
  const int koff = (lane >> 4) * 8;
  const size_t cbase = (size_t)bz * NH;

  auto do_head = [&](int r) {
    const size_t hb = (cbase + 2 + r) * HSTR;
    short8 aq[2], bk[2][2];
#pragma unroll
    for (int kc = 0; kc < 2; ++kc) {
      aq[kc] = *reinterpret_cast<const short8*>(
          qs + hb + (size_t)(m0 + frow) * 64 + kc * 32 + koff);
      bk[0][kc] = *reinterpret_cast<const short8*>(
          ks + hb + (size_t)(n0 + frow) * 64 + kc * 32 + koff);
      bk[1][kc] = *reinterpret_cast<const short8*>(
          ks + hb + (size_t)(n0 + 16 + frow) * 64 + kc * 32 + koff);
    }
    f32x4 acc[2] = {};
#pragma unroll
    for (int jf = 0; jf < 2; ++jf)
#pragma unroll
      for (int kc = 0; kc < 2; ++kc)
        acc[jf] = __builtin_amdgcn_mfma_f32_16x16x32_bf16(aq[kc], bk[jf][kc], acc[jf], 0, 0, 0);
#pragma unroll
    for (int jf = 0; jf < 2; ++jf)
#pragma unroll
      for (int rg = 0; rg < 4; ++rg) {
        int m = (lane >> 4) * 4 + rg;
        int n = jf * 16 + (lane & 15);
        tile[(m * 32 + n) * 60 + r] = f2bf(acc[jf][rg]);
      }
  };

  if (w < 12) {
    const int h0 = w * 4;
#pragma unroll 2
    for (int i = 0; i < 4; ++i) do_head(h0 + i);
  } else {
    const int h0 = 48 + (w - 12) * 3;
#pragma unroll 2
    for (int i = 0; i < 3; ++i) do_head(h0 + i);
  }
  __syncthreads();

  const int mode = mask_mode(triu_mask);
  const size_t maskbase = ((size_t)bg * LQ + m0) * LQ + n0;
  const size_t outbase  = ROLE_OFF + (((size_t)bg * LQ + m0) * LQ + n0) * 60;
  for (int f = tid; f < 7680; f += 1024) {        // 16*32*60/4 float4s
    int e  = f * 4;
    int m  = e / 1920;
    int x  = e - m * 1920;           // n*60 + rr, rr always <= 56
    int n_ = x / 60;
    u16x4 tv = *reinterpret_cast<const u16x4*>(&tile[e]);
    bool mk = mask_at(triu_mask, mode, maskbase + (size_t)m * LQ + n_);
    f32x4 v;
    v[0] = mk ? bf2f(tv[0]) : NEGF;
    v[1] = mk ? bf2f(tv[1]) : NEGF;
    v[2] = mk ? bf2f(tv[2]) : NEGF;
    v[3] = mk ? bf2f(tv[3]) : NEGF;
    __builtin_nontemporal_store(
        v, reinterpret_cast<f32x4*>(&out[outbase + (size_t)m * (LQ * 60) + x]));
  }
}

// ---------------------------------------------------------------------------
// tri/arg logits chunk: block (mt, h, bz), 32 rows x 256; nt output stores.
// grid: (8, 2, cb)
// ---------------------------------------------------------------------------
__global__ __launch_bounds__(256)
void k_ta_chunk(const short* __restrict__ qs, const short* __restrict__ ks,
                const void* __restrict__ word_mask, float* __restrict__ out,
                int b0) {
  const int mt = blockIdx.x, h = blockIdx.y, bz = blockIdx.z;
  const int bg = b0 + bz;
  const int m0 = mt * 32;
  __shared__ uint16_t tile[32 * 256];

  const int tid = threadIdx.x, lane = tid & 63, w = tid >> 6;
  const int frow = lane & 31;
  const int koff = (lane >> 5) * 8;
  const size_t hb = ((size_t)bz * NH + h) * HSTR;

  short8 aq[4];
#pragma unroll
  for (int kc = 0; kc < 4; ++kc)
    aq[kc] = *reinterpret_cast<const short8*>(
        qs + hb + (size_t)(m0 + frow) * 64 + kc * 16 + koff);

  typedef __attribute__((ext_vector_type(16))) float f32x16l;
#pragma unroll
  for (int jn = 0; jn < 2; ++jn) {
    const int ncol0 = w * 64 + jn * 32;
    short8 bk[4];
#pragma unroll
    for (int kc = 0; kc < 4; ++kc)
      bk[kc] = *reinterpret_cast<const short8*>(
          ks + hb + (size_t)(ncol0 + frow) * 64 + kc * 16 + koff);
    f32x16l acc = {};
#pragma unroll
    for (int kc = 0; kc < 4; ++kc)
      acc = __builtin_amdgcn_mfma_f32_32x32x16_bf16(aq[kc], bk[kc], acc, 0, 0, 0);
#pragma unroll
    for (int rg = 0; rg < 16; ++rg) {
      int m = (rg & 3) + 8 * (rg >> 2) + 4 * (lane >> 5);
      int n = ncol0 + (lane & 31);
      tile[m * 256 + n] = f2bf(acc[rg]);
    }
  }
  __syncthreads();

  const int mode = mask_mode(word_mask);
  const size_t maskbase = ((size_t)bg * LQ + m0) * LQ;
  const size_t outbase  = (size_t)h * TA_OFF + ((size_t)bg * LQ + m0) * LQ;
  for (int e = tid; e < 8192; e += 256) {
    int m = e >> 8, n = e & 255;
    bool mk = mask_at(word_mask, mode, maskbase + (size_t)m * LQ + n);
    float val = mk ? bf2f(tile[e]) : NEGF;
    __builtin_nontemporal_store(val, &out[outbase + e]);
  }
}

// ---------------------------------------------------------------------------
// Fallback fused tri/arg (tiny ws): LDS-resident, no scratch. grid (2,16).
// ---------------------------------------------------------------------------
__global__ __launch_bounds__(256)
void k_ta_fused(const float* __restrict__ E,
                const float* __restrict__ triW, const float* __restrict__ triB,
                const float* __restrict__ argW, const float* __restrict__ argB,
                const void* __restrict__ word_mask, float* __restrict__ out) {
  const int h = blockIdx.x, b = blockIdx.y;
  const float* W  = h ? argW : triW;
  const float* Bv = h ? argB : triB;

  __shared__ short As[2][128 * 32];
  __shared__ short Bs[2][128 * 32];
  __shared__ short qk[256 * 128];

  const int tid  = threadIdx.x;
  const int lane = tid & 63;
  const int w    = tid >> 6;
  const int wm   = (w >> 1) * 64, wn = (w & 1) * 64;
  const int srow = tid >> 2;
  const int scol = (tid & 3) * 8;
  const int col_l = lane & 15;
  const int row_h = (lane >> 4) * 4;

  for (int mi = 0; mi < 2; ++mi) {
    const int r0 = mi * 128;
    f32x4 acc[4][4] = {};
    f32x4 ra0[2], ra1[2], rb0[2], rb1[2];
    auto load_regs = [&](int k0) {
      const float* pa0 = E + ((size_t)b * LQ + r0 + srow) * HID + k0 + scol;
      const float* pa1 = E + ((size_t)b * LQ + r0 + 64 + srow) * HID + k0 + scol;
      const float* pb0 = W + (size_t)(srow) * HID + k0 + scol;
      const float* pb1 = W + (size_t)(64 + srow) * HID + k0 + scol;
      ra0[0] = *reinterpret_cast<const f32x4*>(pa0);
      ra0[1] = *reinterpret_cast<const f32x4*>(pa0 + 4);
      ra1[0] = *reinterpret_cast<const f32x4*>(pa1);
      ra1[1] = *reinterpret_cast<const f32x4*>(pa1 + 4);
      rb0[0] = *reinterpret_cast<const f32x4*>(pb0);
      rb0[1] = *reinterpret_cast<const f32x4*>(pb0 + 4);
      rb1[0] = *reinterpret_cast<const f32x4*>(pb1);
      rb1[1] = *reinterpret_cast<const f32x4*>(pb1 + 4);
    };
    auto cvt8 = [&](const f32x4* v) -> short8 {
      short8 r;
      r[0] = (short)f2bf_tr(v[0][0]); r[1] = (short)f2bf_tr(v[0][1]);
      r[2] = (short)f2bf_tr(v[0][2]); r[3] = (short)f2bf_tr(v[0][3]);
      r[4] = (short)f2bf_tr(v[1][0]); r[5] = (short)f2bf_tr(v[1][1]);
      r[6] = (short)f2bf_tr(v[1][2]); r[7] = (short)f2bf_tr(v[1][3]);
      return r;
    };
    auto write_lds = [&](int buf) {
      *reinterpret_cast<short8*>(&As[buf][srow * 32 + scol])        = cvt8(ra0);
      *reinterpret_cast<short8*>(&As[buf][(64 + srow) * 32 + scol]) = cvt8(ra1);
      *reinterpret_cast<short8*>(&Bs[buf][srow * 32 + scol])        = cvt8(rb0);
      *reinterpret_cast<short8*>(&Bs[buf][(64 + srow) * 32 + scol]) = cvt8(rb1);
    };
    load_regs(0); write_lds(0); __syncthreads();
    for (int t = 0; t < 32; ++t) {
      if (t + 1 < 32) load_regs((t + 1) * 32);
      const int buf = t & 1;
      short8 af[4], bfr[4];
#pragma unroll
      for (int i = 0; i < 4; ++i)
        af[i] = *reinterpret_cast<const short8*>(
            &As[buf][(wm + i * 16 + col_l) * 32 + (lane >> 4) * 8]);
#pragma unroll
      for (int j = 0; j < 4; ++j)
        bfr[j] = *reinterpret_cast<const short8*>(
            &Bs[buf][(wn + j * 16 + col_l) * 32 + (lane >> 4) * 8]);
#pragma unroll
      for (int i = 0; i < 4; ++i)
#pragma unroll
        for (int j = 0; j < 4; ++j)
          acc[i][j] = __builtin_amdgcn_mfma_f32_16x16x32_bf16(af[i], bfr[j], acc[i][j], 0, 0, 0);
      __syncthreads();
      if (t + 1 < 32) { write_lds((t + 1) & 1); __syncthreads(); }
    }
#pragma unroll
    for (int j = 0; j < 4; ++j) {
      const int n_loc = wn + j * 16 + col_l;
      const float bias = Bv[n_loc];
      const int d = n_loc & 63;
      const bool odd = d & 1;
      const float invf = rope_invf(d >> 1);
#pragma unroll
      for (int i = 0; i < 4; ++i) {
#pragma unroll
        for (int r = 0; r < 4; ++r) {
          float v  = acc[i][j][r] + bias;
          float vp = __shfl_xor(v, 1, 64);
          int pos = r0 + wm + i * 16 + row_h + r;
          float s, c;
          rope_cs(pos, invf, &s, &c);
          float o = odd ? (v * c + vp * s) : (v * c - vp * s);
          qk[pos * 128 + n_loc] = (short)f2bf(o);
        }
      }
    }
    __syncthreads();
  }

  const int mode = mask_mode(word_mask);
  short8 aq[4][2];
#pragma unroll
  for (int i = 0; i < 4; ++i)
#pragma unroll
    for (int kk = 0; kk < 2; ++kk)
      aq[i][kk] = *reinterpret_cast<const short8*>(
          &qk[(w * 64 + i * 16 + col_l) * 128 + kk * 32 + (lane >> 4) * 8]);

  for (int ncb = 0; ncb < 4; ++ncb) {
    const int nbase = ncb * 64;
    short8 bk[4][2];
#pragma unroll
    for (int j = 0; j < 4; ++j)
#pragma unroll
      for (int kk = 0; kk < 2; ++kk)
        bk[j][kk] = *reinterpret_cast<const short8*>(
            &qk[(nbase + j * 16 + col_l) * 128 + 64 + kk * 32 + (lane >> 4) * 8]);
    f32x4 acc[4][4] = {};
#pragma unroll
    for (int i = 0; i < 4; ++i)
#pragma unroll
      for (int j = 0; j < 4; ++j)
#pragma unroll
        for (int kk = 0; kk < 2; ++kk)
          acc[i][j] = __builtin_amdgcn_mfma_f32_16x16x32_bf16(aq[i][kk], bk[j][kk], acc[i][j], 0, 0, 0);
#pragma unroll
    for (int i = 0; i < 4; ++i)
#pragma unroll
      for (int j = 0; j < 4; ++j)
#pragma unroll
        for (int r = 0; r < 4; ++r) {
          int gm = w * 64 + i * 16 + row_h + r;
          int gn = nbase + j * 16 + col_l;
          size_t mi_ = ((size_t)b * LQ + gm) * LQ + gn;
          bool mk = mask_at(word_mask, mode, mi_);
          out[(size_t)h * TA_OFF + mi_] = mk ? acc[i][j][r] : NEGF;
        }
  }
}

// ---------------------------------------------------------------------------
extern "C" void kernel_launch(void* const* d_in, const int* in_sizes, int n_in,
                              void* d_out, int out_size, void* d_ws, size_t ws_size,
                              hipStream_t stream) {
  (void)in_sizes; (void)n_in; (void)out_size;
  const float* E     = (const float*)d_in[0];
  const float* triW  = (const float*)d_in[1];
  const float* triB  = (const float*)d_in[2];
  const float* argW  = (const float*)d_in[3];
  const float* argB  = (const float*)d_in[4];
  const float* roleW = (const float*)d_in[5];
  const float* roleB = (const float*)d_in[6];
  const void*  wmask = d_in[7];
  const void*  tmask = d_in[8];
  float* out = (float*)d_out;

  const size_t PER_B = (size_t)NH * HSTR * 2 * 2;              // 4,063,232 B
  const size_t PRE   = ((size_t)4096 * HID + (size_t)7936 * HID) * 2;  // 24.65 MB

  int cb_pre = (ws_size > PRE) ? (int)((ws_size - PRE) / PER_B) : 0;
  if (cb_pre > 16) cb_pre = 16;

  if (cb_pre >= 1) {
    short* qs = (short*)d_ws;
    short* ks = qs + (size_t)cb_pre * NH * HSTR;
    short* Eb = ks + (size_t)cb_pre * NH * HSTR;
    short* Wb = Eb + (size_t)4096 * HID;
    k_preconv<<<dim3(2048), dim3(256), 0, stream>>>(E, triW, argW, roleW, Eb, Wb);
    for (int b0 = 0; b0 < 16; b0 += cb_pre) {
      int cbi = (16 - b0 < cb_pre) ? (16 - b0) : cb_pre;
      k_proj_pre<<<dim3(62, 2 * cbi), dim3(256), 0, stream>>>(
          Eb, Wb, triB, argB, roleB, qs, ks, b0);
      k_role6<<<dim3(8, 16, cbi), dim3(1024), 0, stream>>>(qs, ks, tmask, out, b0);
      k_ta_chunk<<<dim3(8, 2, cbi), dim3(256), 0, stream>>>(qs, ks, wmask, out, b0);
    }
    return;
  }

  int cb = (int)(ws_size / PER_B);
  if (cb > 16) cb = 16;
  if (cb >= 1) {
    short* qs = (short*)d_ws;
    short* ks = qs + (size_t)cb * NH * HSTR;
    for (int b0 = 0; b0 < 16; b0 += cb) {
      int cbi = (16 - b0 < cb) ? (16 - b0) : cb;
      k_proj_chunk<<<dim3(62, 2 * cbi), dim3(256), 0, stream>>>(
          E, triW, triB, argW, argB, roleW, roleB, qs, ks, b0);
      k_role6<<<dim3(8, 16, cbi), dim3(1024), 0, stream>>>(qs, ks, tmask, out, b0);
      k_ta_chunk<<<dim3(8, 2, cbi), dim3(256), 0, stream>>>(qs, ks, wmask, out, b0);
    }
  } else {
    short* qs = (short*)d_out;
    short* ks = qs + (size_t)NH * HSTR;
    for (int b0 = 0; b0 < 16; ++b0) {
      k_proj_chunk<<<dim3(62, 2), dim3(256), 0, stream>>>(
          E, triW, triB, argW, argB, roleW, roleB, qs, ks, b0);
      k_role6<<<dim3(8, 16, 1), dim3(1024), 0, stream>>>(qs, ks, tmask, out, b0);
    }
    k_ta_fused<<<dim3(2, 16), dim3(256), 0, stream>>>(E, triW, triB, argW, argB,
                                                      wmask, out);
  }
}

// Round 13
// 234.227 us; speedup vs baseline: 1.0458x; 1.0458x over previous
//
#include <hip/hip_runtime.h>
#include <hip/hip_bf16.h>
#include <stdint.h>

// ---------------------------------------------------------------------------
// OneEventExtracter: proj GEMM (f32 in -> bf16 MFMA) + RoPE + 62-head QK^T.
// B=16, L=256, H=1024, heads: [tri, arg, role0..59], head_dim=64.
// Inputs f32, OUTPUTS FLOAT32. Masked slots = bf16-cast -1e12 exactly.
// R13: revert role to 512thr (R11) + PAIRED-HEAD software pipeline (2 heads'
// loads in flight per wave -> halves exposed L2/L3 latency on the serial
// chain; R12 counters showed role is latency-bound: MfmaUtil 2%, reads
// cached, conflicts negligible). Everything else = R11.
// ---------------------------------------------------------------------------

typedef __attribute__((ext_vector_type(8)))  short short8;
typedef __attribute__((ext_vector_type(4)))  float f32x4;
typedef __attribute__((ext_vector_type(4)))  uint16_t u16x4;

#define LQ    256
#define HID   1024
#define NH    62                   // heads
#define HSTR  16384                // 256 tokens * 64 dims, per head per batch
#define NEGF  (-1000727379968.0f)  // bf16(-1e12) as f32 — matches bf16-cast ref
#define TA_OFF   1048576ULL        // arg output offset (f32 elems)
#define ROLE_OFF 2097152ULL        // role output offset (f32 elems)

__device__ __forceinline__ uint16_t f2bf(float x) {          // RNE
  uint32_t u = __builtin_bit_cast(uint32_t, x);
  return (uint16_t)((u + 0x7FFFu + ((u >> 16) & 1u)) >> 16);
}
__device__ __forceinline__ uint16_t f2bf_tr(float x) {       // truncate (GEMM in)
  return (uint16_t)(__builtin_bit_cast(uint32_t, x) >> 16);
}
__device__ __forceinline__ float bf2f(uint16_t b) {
  uint32_t u = ((uint32_t)b) << 16;
  return __builtin_bit_cast(float, u);
}
__device__ __forceinline__ int mask_mode(const void* p) {
  uint32_t w0 = *(const uint32_t*)p;
  if (w0 == 0x01010101u) return 0;   // bool bytes
  if (w0 == 1u)          return 1;   // int32
  if (w0 == 0x3F803F80u) return 2;   // bf16
  return 3;                          // f32
}
__device__ __forceinline__ bool mask_at(const void* p, int mode, size_t idx) {
  if (mode == 0) return ((const uint8_t*)p)[idx] != 0;
  if (mode == 1) return ((const int*)p)[idx] != 0;
  if (mode == 2) return (((const uint16_t*)p)[idx] & 0x7FFFu) != 0;
  return ((const float*)p)[idx] != 0.0f;
}
__device__ __forceinline__ void rope_cs(int pos, float invf, float* s, float* c) {
  float ang = (float)pos * invf;
  __sincosf(ang, s, c);
}
__device__ __forceinline__ float rope_invf(int p) {
  return exp2f(-(float)p * (13.287712379549449f / 32.0f));
}
__device__ __forceinline__ void gload16(const short* g, short* l) {
  __builtin_amdgcn_global_load_lds(
      (const __attribute__((address_space(1))) void*)g,
      (__attribute__((address_space(3))) void*)l, 16, 0, 0);
}
// m204 bijective XCD swizzle: contiguous work range per XCD.
__device__ __forceinline__ int xcd_swizzle(int l, int nwg) {
  int xcd = l & 7, idx = l >> 3;
  int q = nwg >> 3, r = nwg & 7;
  int base = (xcd < r) ? xcd * (q + 1) : r * (q + 1) + (xcd - r) * q;
  return base + idx;
}

// ---------------------------------------------------------------------------
// Preconvert to TILED bf16: tile = [16 rows][32 k] = 512 elems = 1KB.
// ---------------------------------------------------------------------------
#define EGRP 524288                    // 4096*1024/8
#define WGRP 1015808                   // 7936*1024/8
__global__ __launch_bounds__(256)
void k_preconv(const float* __restrict__ E,
               const float* __restrict__ triW, const float* __restrict__ argW,
               const float* __restrict__ roleW,
               short* __restrict__ Eb, short* __restrict__ Wb) {
  for (int gid = blockIdx.x * 256 + threadIdx.x; gid < EGRP + WGRP;
       gid += gridDim.x * 256) {
    const float* src;
    short* dst;
    if (gid < EGRP) {
      int row = gid >> 7, col8 = gid & 127;
      src = E + (size_t)row * HID + col8 * 8;
      dst = Eb + (((size_t)(row >> 4)) * 32 + (col8 >> 2)) * 512
               + (row & 15) * 32 + (col8 & 3) * 8;
    } else {
      int g = gid - EGRP;
      int row = g >> 7, col8 = g & 127;
      const float* srow = (row < 128) ? triW + (size_t)row * HID
                        : (row < 256) ? argW + (size_t)(row - 128) * HID
                                      : roleW + (size_t)(row - 256) * HID;
      src = srow + col8 * 8;
      dst = Wb + (((size_t)(row >> 4)) * 32 + (col8 >> 2)) * 512
               + (row & 15) * 32 + (col8 & 3) * 8;
    }
    f32x4 v0 = *reinterpret_cast<const f32x4*>(src);
    f32x4 v1 = *reinterpret_cast<const f32x4*>(src + 4);
    short8 r;
    r[0] = (short)f2bf_tr(v0[0]); r[1] = (short)f2bf_tr(v0[1]);
    r[2] = (short)f2bf_tr(v0[2]); r[3] = (short)f2bf_tr(v0[3]);
    r[4] = (short)f2bf_tr(v1[0]); r[5] = (short)f2bf_tr(v1[1]);
    r[6] = (short)f2bf_tr(v1[2]); r[7] = (short)f2bf_tr(v1[3]);
    *reinterpret_cast<short8*>(dst) = r;
  }
}

// ---------------------------------------------------------------------------
// Proj GEMM (tiled bf16, global_load_lds 1KB bursts): 128x128 tile, BK=32.
// grid: (62, 2*cb), XCD-swizzled. RoPE epilogue -> qs/ks [c][head][token][64].
// ---------------------------------------------------------------------------
__global__ __launch_bounds__(256)
void k_proj_pre(const short* __restrict__ Eb, const short* __restrict__ Wb,
                const float* __restrict__ triB, const float* __restrict__ argB,
                const float* __restrict__ roleB,
                short* __restrict__ qs, short* __restrict__ ks, int b0) {
  const int nwg = 62 * gridDim.y;
  const int nl  = xcd_swizzle(blockIdx.x + 62 * blockIdx.y, nwg);
  const int nb = nl % 62;             // 0..61
  const int mb = nl / 62;             // chunk-local 128-row tile
  const int n0 = nb * 128;
  const int mrow0 = b0 * LQ + mb * 128;
  const int lrow0 = mb * 128;

  const float* Bv;
  if (nb == 0)      Bv = triB;
  else if (nb == 1) Bv = argB;
  else              Bv = roleB + (n0 - 256);

  __shared__ short As[2][128 * 32];
  __shared__ short Bs[2][128 * 32];

  const int tid  = threadIdx.x;
  const int lane = tid & 63;
  const int w    = tid >> 6;
  const int wm   = (w >> 1) * 64, wn = (w & 1) * 64;
  const int l8   = lane * 8;
  const int mt0  = mrow0 >> 4;        // 16-row tile base (A)
  const int nt0  = n0 >> 4;           // 16-row tile base (B)

  f32x4 acc[4][4] = {};

  auto stage = [&](int buf, int kt) {
#pragma unroll
    for (int cc = 0; cc < 2; ++cc) {
      const int c = w * 2 + cc;        // 16-row subtile 0..7
      gload16(Eb + ((size_t)(mt0 + c) * 32 + kt) * 512 + l8, &As[buf][c * 512]);
      gload16(Wb + ((size_t)(nt0 + c) * 32 + kt) * 512 + l8, &Bs[buf][c * 512]);
    }
  };

  stage(0, 0);
  __syncthreads();
  for (int t = 0; t < 32; ++t) {
    const int buf = t & 1;
    if (t + 1 < 32) stage(buf ^ 1, t + 1);
    short8 af[4], bfr[4];
#pragma unroll
    for (int i = 0; i < 4; ++i)
      af[i] = *reinterpret_cast<const short8*>(
          &As[buf][(wm + i * 16 + (lane & 15)) * 32 + (lane >> 4) * 8]);
#pragma unroll
    for (int j = 0; j < 4; ++j)
      bfr[j] = *reinterpret_cast<const short8*>(
          &Bs[buf][(wn + j * 16 + (lane & 15)) * 32 + (lane >> 4) * 8]);
#pragma unroll
    for (int i = 0; i < 4; ++i)
#pragma unroll
      for (int j = 0; j < 4; ++j)
        acc[i][j] = __builtin_amdgcn_mfma_f32_16x16x32_bf16(af[i], bfr[j], acc[i][j], 0, 0, 0);
    __syncthreads();
  }

  // Epilogue: bias + RoPE + scatter bf16 to [c][head][token][64].
  const int col_l = lane & 15;
  const int row_h = (lane >> 4) * 4;
#pragma unroll
  for (int j = 0; j < 4; ++j) {
    const int n_loc = wn + j * 16 + col_l;
    const int gcol  = n0 + n_loc;
    const float bias = Bv[n_loc];
    const int d    = gcol & 63;
    const int head = gcol >> 7;
    const bool is_k = (gcol >> 6) & 1;
    const bool odd = d & 1;
    const float invf = rope_invf(d >> 1);
    short* dst = is_k ? ks : qs;
#pragma unroll
    for (int i = 0; i < 4; ++i) {
#pragma unroll
      for (int r = 0; r < 4; ++r) {
        float v  = acc[i][j][r] + bias;
        float vp = __shfl_xor(v, 1, 64);
        int tl  = lrow0 + wm + i * 16 + row_h + r;   // chunk-local token row
        int pos = tl & (LQ - 1);
        float s, c;
        rope_cs(pos, invf, &s, &c);
        float o = odd ? (v * c + vp * s) : (v * c - vp * s);
        dst[((size_t)(tl >> 8) * NH + head) * HSTR + (size_t)pos * 64 + d] =
            (short)f2bf(o);
      }
    }
  }
}

// ---------------------------------------------------------------------------
// Fallback proj (f32 inputs, reg-staged cvt) — same epilogue layout.
// ---------------------------------------------------------------------------
__global__ __launch_bounds__(256)
void k_proj_chunk(const float* __restrict__ E,
                  const float* __restrict__ triW, const float* __restrict__ triB,
                  const float* __restrict__ argW, const float* __restrict__ argB,
                  const float* __restrict__ roleW, const float* __restrict__ roleB,
                  short* __restrict__ qs, short* __restrict__ ks, int b0) {
  const int nb = blockIdx.x;
  const int mb = blockIdx.y;
  const int n0 = nb * 128;
  const int mrow0 = b0 * LQ + mb * 128;
  const int lrow0 = mb * 128;

  const float* W;  const float* Bv;
  if (nb == 0)      { W = triW;                             Bv = triB; }
  else if (nb == 1) { W = argW;                             Bv = argB; }
  else              { W = roleW + (size_t)(n0 - 256) * HID; Bv = roleB + (n0 - 256); }

  __shared__ short As[2][128 * 32];
  __shared__ short Bs[2][128 * 32];

  const int tid  = threadIdx.x;
  const int lane = tid & 63;
  const int w    = tid >> 6;
  const int wm   = (w >> 1) * 64, wn = (w & 1) * 64;
  const int srow = tid >> 2;
  const int scol = (tid & 3) * 8;

  f32x4 acc[4][4] = {};
  f32x4 ra0[2], ra1[2], rb0[2], rb1[2];

  auto load_regs = [&](int k0) {
    const float* pa0 = E + (size_t)(mrow0 + srow) * HID + k0 + scol;
    const float* pa1 = E + (size_t)(mrow0 + 64 + srow) * HID + k0 + scol;
    const float* pb0 = W + (size_t)(srow) * HID + k0 + scol;
    const float* pb1 = W + (size_t)(64 + srow) * HID + k0 + scol;
    ra0[0] = *reinterpret_cast<const f32x4*>(pa0);
    ra0[1] = *reinterpret_cast<const f32x4*>(pa0 + 4);
    ra1[0] = *reinterpret_cast<const f32x4*>(pa1);
    ra1[1] = *reinterpret_cast<const f32x4*>(pa1 + 4);
    rb0[0] = *reinterpret_cast<const f32x4*>(pb0);
    rb0[1] = *reinterpret_cast<const f32x4*>(pb0 + 4);
    rb1[0] = *reinterpret_cast<const f32x4*>(pb1);
    rb1[1] = *reinterpret_cast<const f32x4*>(pb1 + 4);
  };
  auto cvt8 = [&](const f32x4* v) -> short8 {
    short8 r;
    r[0] = (short)f2bf_tr(v[0][0]); r[1] = (short)f2bf_tr(v[0][1]);
    r[2] = (short)f2bf_tr(v[0][2]); r[3] = (short)f2bf_tr(v[0][3]);
    r[4] = (short)f2bf_tr(v[1][0]); r[5] = (short)f2bf_tr(v[1][1]);
    r[6] = (short)f2bf_tr(v[1][2]); r[7] = (short)f2bf_tr(v[1][3]);
    return r;
  };
  auto write_lds = [&](int buf) {
    *reinterpret_cast<short8*>(&As[buf][srow * 32 + scol])        = cvt8(ra0);
    *reinterpret_cast<short8*>(&As[buf][(64 + srow) * 32 + scol]) = cvt8(ra1);
    *reinterpret_cast<short8*>(&Bs[buf][srow * 32 + scol])        = cvt8(rb0);
    *reinterpret_cast<short8*>(&Bs[buf][(64 + srow) * 32 + scol]) = cvt8(rb1);
  };

  load_regs(0); write_lds(0); __syncthreads();
  const int NT = HID / 32;
  for (int t = 0; t < NT; ++t) {
    if (t + 1 < NT) load_regs((t + 1) * 32);
    const int buf = t & 1;
    short8 af[4], bfr[4];
#pragma unroll
    for (int i = 0; i < 4; ++i)
      af[i] = *reinterpret_cast<const short8*>(
          &As[buf][(wm + i * 16 + (lane & 15)) * 32 + (lane >> 4) * 8]);
#pragma unroll
    for (int j = 0; j < 4; ++j)
      bfr[j] = *reinterpret_cast<const short8*>(
          &Bs[buf][(wn + j * 16 + (lane & 15)) * 32 + (lane >> 4) * 8]);
#pragma unroll
    for (int i = 0; i < 4; ++i)
#pragma unroll
      for (int j = 0; j < 4; ++j)
        acc[i][j] = __builtin_amdgcn_mfma_f32_16x16x32_bf16(af[i], bfr[j], acc[i][j], 0, 0, 0);
    __syncthreads();
    if (t + 1 < NT) { write_lds((t + 1) & 1); __syncthreads(); }
  }

  const int col_l = lane & 15;
  const int row_h = (lane >> 4) * 4;
#pragma unroll
  for (int j = 0; j < 4; ++j) {
    const int n_loc = wn + j * 16 + col_l;
    const int gcol  = n0 + n_loc;
    const float bias = Bv[n_loc];
    const int d    = gcol & 63;
    const int head = gcol >> 7;
    const bool is_k = (gcol >> 6) & 1;
    const bool odd = d & 1;
    const float invf = rope_invf(d >> 1);
    short* dst = is_k ? ks : qs;
#pragma unroll
    for (int i = 0; i < 4; ++i) {
#pragma unroll
      for (int r = 0; r < 4; ++r) {
        float v  = acc[i][j][r] + bias;
        float vp = __shfl_xor(v, 1, 64);
        int tl  = lrow0 + wm + i * 16 + row_h + r;
        int pos = tl & (LQ - 1);
        float s, c;
        rope_cs(pos, invf, &s, &c);
        float o = odd ? (v * c + vp * s) : (v * c - vp * s);
        dst[((size_t)(tl >> 8) * NH + head) * HSTR + (size_t)pos * 64 + d] =
            (short)f2bf(o);
      }
    }
  }
}

// ---------------------------------------------------------------------------
// Role logits v7: 512 thr (8 waves), heads {8,8,8,8,7,7,7,7}, PAIRED-HEAD
// pipeline (two heads' 12 loads in flight before MFMA). nt f32x4 writeout.
// grid: (8, 16, cb), XCD-swizzled by batch.
// ---------------------------------------------------------------------------
__global__ __launch_bounds__(512)
void k_role7(const short* __restrict__ qs, const short* __restrict__ ks,
             const void* __restrict__ triu_mask, float* __restrict__ out,
             int b0) {
  const int nwg = gridDim.z * 128;    // always divisible by 8
  const int nl  = xcd_swizzle(blockIdx.x + 8 * blockIdx.y + 128 * blockIdx.z,
                              nwg);
  const int bz  = nl >> 7;
  const int rem = nl & 127;
  const int mt  = rem >> 3, nt = rem & 7;
  const int bg = b0 + bz;
  const int m0 = mt * 16, n0 = nt * 32;
  __shared__ uint16_t tile[16 * 32 * 60];   // 60 KB

  const int tid = threadIdx.x, lane = tid & 63, w = tid >> 6;
  const int frow = lane & 15;
  const int koff = (lane >> 4) * 8;
  const size_t cbase = (size_t)bz * NH;

  const short* qrow = qs + (size_t)(m0 + frow) * 64 + koff;
  const short* krow0 = ks + (size_t)(n0 + frow) * 64 + koff;
  const short* krow1 = ks + (size_t)(n0 + 16 + frow) * 64 + koff;

  auto load_head = [&](int r, short8* aq, short8 (*bk)[2]) {
    const size_t hb = (cbase + 2 + r) * HSTR;
#pragma unroll
    for (int kc = 0; kc < 2; ++kc) {
      aq[kc]    = *reinterpret_cast<const short8*>(qrow + hb + kc * 32);
      bk[0][kc] = *reinterpret_cast<const short8*>(krow0 + hb + kc * 32);
      bk[1][kc] = *reinterpret_cast<const short8*>(krow1 + hb + kc * 32);
    }
  };
  auto mfma_store = [&](int r, const short8* aq, const short8 (*bk)[2]) {
    f32x4 acc[2] = {};
#pragma unroll
    for (int jf = 0; jf < 2; ++jf)
#pragma unroll
      for (int kc = 0; kc < 2; ++kc)
        acc[jf] = __builtin_amdgcn_mfma_f32_16x16x32_bf16(aq[kc], bk[jf][kc], acc[jf], 0, 0, 0);
#pragma unroll
    for (int jf = 0; jf < 2; ++jf)
#pragma unroll
      for (int rg = 0; rg < 4; ++rg) {
        int m = (lane >> 4) * 4 + rg;
        int n = jf * 16 + (lane & 15);
        tile[(m * 32 + n) * 60 + r] = f2bf(acc[jf][rg]);
      }
  };

  const int hstart = (w < 4) ? w * 8 : 32 + (w - 4) * 7;
  const int hcnt   = (w < 4) ? 8 : 7;
  int i = 0;
  for (; i + 1 < hcnt; i += 2) {
    short8 aqA[2], bkA[2][2], aqB[2], bkB[2][2];
    load_head(hstart + i,     aqA, bkA);
    load_head(hstart + i + 1, aqB, bkB);
    mfma_store(hstart + i,     aqA, bkA);
    mfma_store(hstart + i + 1, aqB, bkB);
  }
  if (i < hcnt) {
    short8 aqA[2], bkA[2][2];
    load_head(hstart + i, aqA, bkA);
    mfma_store(hstart + i, aqA, bkA);
  }
  __syncthreads();

  const int mode = mask_mode(triu_mask);
  const size_t maskbase = ((size_t)bg * LQ + m0) * LQ + n0;
  const size_t outbase  = ROLE_OFF + (((size_t)bg * LQ + m0) * LQ + n0) * 60;
  for (int f = tid; f < 7680; f += 512) {         // 16*32*60/4 float4s
    int e  = f * 4;
    int m  = e / 1920;
    int x  = e - m * 1920;           // n*60 + rr, rr always <= 56
    int n_ = x / 60;
    u16x4 tv = *reinterpret_cast<const u16x4*>(&tile[e]);
    bool mk = mask_at(triu_mask, mode, maskbase + (size_t)m * LQ + n_);
    f32x4 v;
    v[0] = mk ? bf2f(tv[0]) : NEGF;
    v[1] = mk ? bf2f(tv[1]) : NEGF;
    v[2] = mk ? bf2f(tv[2]) : NEGF;
    v[3] = mk ? bf2f(tv[3]) : NEGF;
    __builtin_nontemporal_store(
        v, reinterpret_cast<f32x4*>(&out[outbase + (size_t)m * (LQ * 60) + x]));
  }
}

// ---------------------------------------------------------------------------
// tri/arg logits chunk: block (mt, h, bz), 32 rows x 256; nt output stores.
// grid: (8, 2, cb)
// ---------------------------------------------------------------------------
__global__ __launch_bounds__(256)
void k_ta_chunk(const short* __restrict__ qs, const short* __restrict__ ks,
                const void* __restrict__ word_mask, float* __restrict__ out,
                int b0) {
  const int mt = blockIdx.x, h = blockIdx.y, bz = blockIdx.z;
  const int bg = b0 + bz;
  const int m0 = mt * 32;
  __shared__ uint16_t tile[32 * 256];

  const int tid = threadIdx.x, lane = tid & 63, w = tid >> 6;
  const int frow = lane & 31;
  const int koff = (lane >> 5) * 8;
  const size_t hb = ((size_t)bz * NH + h) * HSTR;

  short8 aq[4];
#pragma unroll
  for (int kc = 0; kc < 4; ++kc)
    aq[kc] = *reinterpret_cast<const short8*>(
        qs + hb + (size_t)(m0 + frow) * 64 + kc * 16 + koff);

  typedef __attribute__((ext_vector_type(16))) float f32x16l;
#pragma unroll
  for (int jn = 0; jn < 2; ++jn) {
    const int ncol0 = w * 64 + jn * 32;
    short8 bk[4];
#pragma unroll
    for (int kc = 0; kc < 4; ++kc)
      bk[kc] = *reinterpret_cast<const short8*>(
          ks + hb + (size_t)(ncol0 + frow) * 64 + kc * 16 + koff);
    f32x16l acc = {};
#pragma unroll
    for (int kc = 0; kc < 4; ++kc)
      acc = __builtin_amdgcn_mfma_f32_32x32x16_bf16(aq[kc], bk[kc], acc, 0, 0, 0);
#pragma unroll
    for (int rg = 0; rg < 16; ++rg) {
      int m = (rg & 3) + 8 * (rg >> 2) + 4 * (lane >> 5);
      int n = ncol0 + (lane & 31);
      tile[m * 256 + n] = f2bf(acc[rg]);
    }
  }
  __syncthreads();

  const int mode = mask_mode(word_mask);
  const size_t maskbase = ((size_t)bg * LQ + m0) * LQ;
  const size_t outbase  = (size_t)h * TA_OFF + ((size_t)bg * LQ + m0) * LQ;
  for (int e = tid; e < 8192; e += 256) {
    int m = e >> 8, n = e & 255;
    bool mk = mask_at(word_mask, mode, maskbase + (size_t)m * LQ + n);
    float val = mk ? bf2f(tile[e]) : NEGF;
    __builtin_nontemporal_store(val, &out[outbase + e]);
  }
}

// ---------------------------------------------------------------------------
// Fallback fused tri/arg (tiny ws): LDS-resident, no scratch. grid (2,16).
// ---------------------------------------------------------------------------
__global__ __launch_bounds__(256)
void k_ta_fused(const float* __restrict__ E,
                const float* __restrict__ triW, const float* __restrict__ triB,
                const float* __restrict__ argW, const float* __restrict__ argB,
                const void* __restrict__ word_mask, float* __restrict__ out) {
  const int h = blockIdx.x, b = blockIdx.y;
  const float* W  = h ? argW : triW;
  const float* Bv = h ? argB : triB;

  __shared__ short As[2][128 * 32];
  __shared__ short Bs[2][128 * 32];
  __shared__ short qk[256 * 128];

  const int tid  = threadIdx.x;
  const int lane = tid & 63;
  const int w    = tid >> 6;
  const int wm   = (w >> 1) * 64, wn = (w & 1) * 64;
  const int srow = tid >> 2;
  const int scol = (tid & 3) * 8;
  const int col_l = lane & 15;
  const int row_h = (lane >> 4) * 4;

  for (int mi = 0; mi < 2; ++mi) {
    const int r0 = mi * 128;
    f32x4 acc[4][4] = {};
    f32x4 ra0[2], ra1[2], rb0[2], rb1[2];
    auto load_regs = [&](int k0) {
      const float* pa0 = E + ((size_t)b * LQ + r0 + srow) * HID + k0 + scol;
      const float* pa1 = E + ((size_t)b * LQ + r0 + 64 + srow) * HID + k0 + scol;
      const float* pb0 = W + (size_t)(srow) * HID + k0 + scol;
      const float* pb1 = W + (size_t)(64 + srow) * HID + k0 + scol;
      ra0[0] = *reinterpret_cast<const f32x4*>(pa0);
      ra0[1] = *reinterpret_cast<const f32x4*>(pa0 + 4);
      ra1[0] = *reinterpret_cast<const f32x4*>(pa1);
      ra1[1] = *reinterpret_cast<const f32x4*>(pa1 + 4);
      rb0[0] = *reinterpret_cast<const f32x4*>(pb0);
      rb0[1] = *reinterpret_cast<const f32x4*>(pb0 + 4);
      rb1[0] = *reinterpret_cast<const f32x4*>(pb1);
      rb1[1] = *reinterpret_cast<const f32x4*>(pb1 + 4);
    };
    auto cvt8 = [&](const f32x4* v) -> short8 {
      short8 r;
      r[0] = (short)f2bf_tr(v[0][0]); r[1] = (short)f2bf_tr(v[0][1]);
      r[2] = (short)f2bf_tr(v[0][2]); r[3] = (short)f2bf_tr(v[0][3]);
      r[4] = (short)f2bf_tr(v[1][0]); r[5] = (short)f2bf_tr(v[1][1]);
      r[6] = (short)f2bf_tr(v[1][2]); r[7] = (short)f2bf_tr(v[1][3]);
      return r;
    };
    auto write_lds = [&](int buf) {
      *reinterpret_cast<short8*>(&As[buf][srow * 32 + scol])        = cvt8(ra0);
      *reinterpret_cast<short8*>(&As[buf][(64 + srow) * 32 + scol]) = cvt8(ra1);
      *reinterpret_cast<short8*>(&Bs[buf][srow * 32 + scol])        = cvt8(rb0);
      *reinterpret_cast<short8*>(&Bs[buf][(64 + srow) * 32 + scol]) = cvt8(rb1);
    };
    load_regs(0); write_lds(0); __syncthreads();
    for (int t = 0; t < 32; ++t) {
      if (t + 1 < 32) load_regs((t + 1) * 32);
      const int buf = t & 1;
      short8 af[4], bfr[4];
#pragma unroll
      for (int i = 0; i < 4; ++i)
        af[i] = *reinterpret_cast<const short8*>(
            &As[buf][(wm + i * 16 + col_l) * 32 + (lane >> 4) * 8]);
#pragma unroll
      for (int j = 0; j < 4; ++j)
        bfr[j] = *reinterpret_cast<const short8*>(
            &Bs[buf][(wn + j * 16 + col_l) * 32 + (lane >> 4) * 8]);
#pragma unroll
      for (int i = 0; i < 4; ++i)
#pragma unroll
        for (int j = 0; j < 4; ++j)
          acc[i][j] = __builtin_amdgcn_mfma_f32_16x16x32_bf16(af[i], bfr[j], acc[i][j], 0, 0, 0);
      __syncthreads();
      if (t + 1 < 32) { write_lds((t + 1) & 1); __syncthreads(); }
    }
#pragma unroll
    for (int j = 0; j < 4; ++j) {
      const int n_loc = wn + j * 16 + col_l;
      const float bias = Bv[n_loc];
      const int d = n_loc & 63;
      const bool odd = d & 1;
      const float invf = rope_invf(d >> 1);
#pragma unroll
      for (int i = 0; i < 4; ++i) {
#pragma unroll
        for (int r = 0; r < 4; ++r) {
          float v  = acc[i][j][r] + bias;
          float vp = __shfl_xor(v, 1, 64);
          int pos = r0 + wm + i * 16 + row_h + r;
          float s, c;
          rope_cs(pos, invf, &s, &c);
          float o = odd ? (v * c + vp * s) : (v * c - vp * s);
          qk[pos * 128 + n_loc] = (short)f2bf(o);
        }
      }
    }
    __syncthreads();
  }

  const int mode = mask_mode(word_mask);
  short8 aq[4][2];
#pragma unroll
  for (int i = 0; i < 4; ++i)
#pragma unroll
    for (int kk = 0; kk < 2; ++kk)
      aq[i][kk] = *reinterpret_cast<const short8*>(
          &qk[(w * 64 + i * 16 + col_l) * 128 + kk * 32 + (lane >> 4) * 8]);

  for (int ncb = 0; ncb < 4; ++ncb) {
    const int nbase = ncb * 64;
    short8 bk[4][2];
#pragma unroll
    for (int j = 0; j < 4; ++j)
#pragma unroll
      for (int kk = 0; kk < 2; ++kk)
        bk[j][kk] = *reinterpret_cast<const short8*>(
            &qk[(nbase + j * 16 + col_l) * 128 + 64 + kk * 32 + (lane >> 4) * 8]);
    f32x4 acc[4][4] = {};
#pragma unroll
    for (int i = 0; i < 4; ++i)
#pragma unroll
      for (int j = 0; j < 4; ++j)
#pragma unroll
        for (int kk = 0; kk < 2; ++kk)
          acc[i][j] = __builtin_amdgcn_mfma_f32_16x16x32_bf16(aq[i][kk], bk[j][kk], acc[i][j], 0, 0, 0);
#pragma unroll
    for (int i = 0; i < 4; ++i)
#pragma unroll
      for (int j = 0; j < 4; ++j)
#pragma unroll
        for (int r = 0; r < 4; ++r) {
          int gm = w * 64 + i * 16 + row_h + r;
          int gn = nbase + j * 16 + col_l;
          size_t mi_ = ((size_t)b * LQ + gm) * LQ + gn;
          bool mk = mask_at(word_mask, mode, mi_);
          out[(size_t)h * TA_OFF + mi_] = mk ? acc[i][j][r] : NEGF;
        }
  }
}

// ---------------------------------------------------------------------------
extern "C" void kernel_launch(void* const* d_in, const int* in_sizes, int n_in,
                              void* d_out, int out_size, void* d_ws, size_t ws_size,
                              hipStream_t stream) {
  (void)in_sizes; (void)n_in; (void)out_size;
  const float* E     = (const float*)d_in[0];
  const float* triW  = (const float*)d_in[1];
  const float* triB  = (const float*)d_in[2];
  const float* argW  = (const float*)d_in[3];
  const float* argB  = (const float*)d_in[4];
  const float* roleW = (const float*)d_in[5];
  const float* roleB = (const float*)d_in[6];
  const void*  wmask = d_in[7];
  const void*  tmask = d_in[8];
  float* out = (float*)d_out;

  const size_t PER_B = (size_t)NH * HSTR * 2 * 2;              // 4,063,232 B
  const size_t PRE   = ((size_t)4096 * HID + (size_t)7936 * HID) * 2;  // 24.65 MB

  int cb_pre = (ws_size > PRE) ? (int)((ws_size - PRE) / PER_B) : 0;
  if (cb_pre > 16) cb_pre = 16;

  if (cb_pre >= 1) {
    short* qs = (short*)d_ws;
    short* ks = qs + (size_t)cb_pre * NH * HSTR;
    short* Eb = ks + (size_t)cb_pre * NH * HSTR;
    short* Wb = Eb + (size_t)4096 * HID;
    k_preconv<<<dim3(2048), dim3(256), 0, stream>>>(E, triW, argW, roleW, Eb, Wb);
    for (int b0 = 0; b0 < 16; b0 += cb_pre) {
      int cbi = (16 - b0 < cb_pre) ? (16 - b0) : cb_pre;
      k_proj_pre<<<dim3(62, 2 * cbi), dim3(256), 0, stream>>>(
          Eb, Wb, triB, argB, roleB, qs, ks, b0);
      k_role7<<<dim3(8, 16, cbi), dim3(512), 0, stream>>>(qs, ks, tmask, out, b0);
      k_ta_chunk<<<dim3(8, 2, cbi), dim3(256), 0, stream>>>(qs, ks, wmask, out, b0);
    }
    return;
  }

  int cb = (int)(ws_size / PER_B);
  if (cb > 16) cb = 16;
  if (cb >= 1) {
    short* qs = (short*)d_ws;
    short* ks = qs + (size_t)cb * NH * HSTR;
    for (int b0 = 0; b0 < 16; b0 += cb) {
      int cbi = (16 - b0 < cb) ? (16 - b0) : cb;
      k_proj_chunk<<<dim3(62, 2 * cbi), dim3(256), 0, stream>>>(
          E, triW, triB, argW, argB, roleW, roleB, qs, ks, b0);
      k_role7<<<dim3(8, 16, cbi), dim3(512), 0, stream>>>(qs, ks, tmask, out, b0);
      k_ta_chunk<<<dim3(8, 2, cbi), dim3(256), 0, stream>>>(qs, ks, wmask, out, b0);
    }
  } else {
    short* qs = (short*)d_out;
    short* ks = qs + (size_t)NH * HSTR;
    for (int b0 = 0; b0 < 16; ++b0) {
      k_proj_chunk<<<dim3(62, 2), dim3(256), 0, stream>>>(
          E, triW, triB, argW, argB, roleW, roleB, qs, ks, b0);
      k_role7<<<dim3(8, 16, 1), dim3(512), 0, stream>>>(qs, ks, tmask, out, b0);
    }
    k_ta_fused<<<dim3(2, 16), dim3(256), 0, stream>>>(E, triW, triB, argW, argB,
                                                      wmask, out);
  }
}